// Round 7
// baseline (6830.026 us; speedup 1.0000x reference)
//
#include <hip/hip_runtime.h>

// GumbelDecoderEncoder: B=16384, E=256, V=128, T=16, TAU=1.
// Key facts exploited:
//  * y is numerically EXACTLY one-hot or zero, so input-side matmuls are
//    table lookups (DecTab/EncTab row 128 = zero-token case).
//  * argmax(softmax((l+g)/tau)) == argmax(l+g).
//  * Encoder sieve can never fire: reconst = final encoder state.
//  * Row-independent; decoder hidden state is wave-private LDS.
// History: R2 fused MFMA encoder (direct loads) = no spill but latency-flat.
// R3/R4/R6: every variant with the deep register prefetch spills to scratch
// (R6 standalone enc: FETCH 5.6GB/WRITE 1.8GB, 3.34ms, L2 thrashed).
// R6 dec at 4 rows/wave = 4096 waves x 768KB WdhhT/step = 50GB L2 (1.46ms
// floor) -> ~2.4ms.
// R7 (this round):
//  * enc_kernel: R2-style DIRECT B loads (3 live frags; the prefetch regs
//    were the spill poison) + 16 rows/block (1024 blocks): acc halves to
//    48 regs, ~4 blocks/CU -> TLP hides L2 latency instead of registers.
//    Per-accumulator MFMA product order unchanged -> encoder numerics
//    identical to R2/R6.
//  * dec_kernel: back to 8 rows/wave (R0's exact proven arithmetic, 128
//    VGPR, no spill): halves weight streaming vs R6 (25GB L2, 0.73ms floor)
//    at 4 blocks/CU standalone occupancy.
// ws: 722432 floats + 256KB tok = 3,151,872 bytes.

namespace {
constexpr int kB  = 16384;
constexpr int kE  = 256;
constexpr int kV  = 128;
constexpr int kT  = 16;
constexpr int kG3 = 768;

constexpr int kOffWdhhT  = 0;                       // [256][768] f32 dec Whh^T (k-major)
constexpr int kOffWe2dT  = kG3 * kE;                // [256][128] f32
constexpr int kOffDecTab = kOffWe2dT + kV * kE;     // [129][768] f32
constexpr int kOffEncTab = kOffDecTab + 129 * kG3;  // [129][768] f32
constexpr int kOffBTab   = kOffEncTab + 129 * kG3;  // enc Whh bf16 3-split (u16)
constexpr int kBCount    = 32 * kG3 * 8;            // 196608 u16 per split level
constexpr int kOffTok    = kOffBTab + (3 * kBCount) / 2;  // [16][16384] u8
// ws bytes: 722432*4 + 262144 = 3,151,872
}

typedef short bf16x8 __attribute__((ext_vector_type(8)));  // 8 bf16 as i16 (4 VGPRs)
typedef float f32x4  __attribute__((ext_vector_type(4)));
typedef unsigned short u16;
typedef unsigned char u8;

__device__ __forceinline__ float sigmf(float v) { return 1.0f / (1.0f + expf(-v)); }
__device__ __forceinline__ float gumbelf(float u) {
  return -logf(-logf(u + 1e-10f) + 1e-10f);
}

__device__ __forceinline__ f32x4 mfma16(bf16x8 a, bf16x8 b, f32x4 c) {
  return __builtin_amdgcn_mfma_f32_16x16x32_bf16(a, b, c, 0, 0, 0);
}

struct Bf3 { bf16x8 h, m, l; };

// exact 3-way bf16 split: f = hi + mid + f2 exactly (truncating Dekker split),
// lo = trunc-to-bf16(f2); dropped bits are < 2^-24 relative.
__device__ __forceinline__ Bf3 split3(float4 a, float4 b) {
  const float v[8] = {a.x, a.y, a.z, a.w, b.x, b.y, b.z, b.w};
  union { bf16x8 b8; u16 u[8]; } H, M, L;
#pragma unroll
  for (int e = 0; e < 8; ++e) {
    const float f = v[e];
    const unsigned hb = __float_as_uint(f) & 0xffff0000u;
    const float f1 = f - __uint_as_float(hb);
    const unsigned mb = __float_as_uint(f1) & 0xffff0000u;
    const float f2 = f1 - __uint_as_float(mb);
    H.u[e] = (u16)(hb >> 16);
    M.u[e] = (u16)(mb >> 16);
    L.u[e] = (u16)(__float_as_uint(f2) >> 16);
  }
  Bf3 r; r.h = H.b8; r.m = M.b8; r.l = L.b8;
  return r;
}

// swizzled henc index: 8-float chunks XORed by row&7 -> spread A-read banks
__device__ __forceinline__ int hidx(int row, int col) {
  return row * kE + ((((col >> 3) ^ (row & 7)) << 3) | (col & 7));
}

// ---- prepass 1: k-major transposes of dec Whh and We2d ----
__global__ void prep_transpose(const float* __restrict__ dWhh,
                               const float* __restrict__ We2d,
                               float* __restrict__ ws) {
  const int n1 = kG3 * kE;
  const int n2 = n1 + kV * kE;
  for (int i = blockIdx.x * blockDim.x + threadIdx.x; i < n2;
       i += gridDim.x * blockDim.x) {
    if (i < n1) {
      const int k = i / kG3, j = i - k * kG3;
      ws[i] = dWhh[j * kE + k];
    } else {
      const int t = i - n1;
      const int k = t / kV, v = t - k * kV;
      ws[i] = We2d[v * kE + k];
    }
  }
}

// ---- prepass 2: token->gi tables (v==128 is the zero-token row) ----
__global__ void prep_tables(const float* __restrict__ Wih,
                            const float* __restrict__ Wd2e,
                            const float* __restrict__ bd2e,
                            const float* __restrict__ bih,
                            float* __restrict__ tab) {
  const int i = blockIdx.x * blockDim.x + threadIdx.x;
  if (i >= 129 * kG3) return;
  const int v = i / kG3, j = i - v * kG3;
  const float* wr = Wih + j * kE;
  float acc = 0.0f;
  if (v < kV) {
    for (int k = 0; k < kE; ++k) acc = fmaf(wr[k], Wd2e[k * kV + v] + bd2e[k], acc);
  } else {
    for (int k = 0; k < kE; ++k) acc = fmaf(wr[k], bd2e[k], acc);
  }
  tab[i] = acc + bih[j];
}

// ---- prepass 3: enc Whh^T -> bf16 3-way split MFMA B-fragment table ----
// record idx = kg*768 + j (kg = k/8), holds e=0..7 with k = kg*8+e.
__global__ void prep_bsplit(const float* __restrict__ eWhh,
                            u16* __restrict__ bt) {
  const int idx = blockIdx.x * blockDim.x + threadIdx.x;
  if (idx >= 32 * kG3) return;
  const int j = idx % kG3;
  const int kg = idx / kG3;
  u16* ph = bt + (size_t)idx * 8;
  u16* pm = ph + kBCount;
  u16* pl = pm + kBCount;
  const float* src = eWhh + j * kE + kg * 8;
#pragma unroll
  for (int e = 0; e < 8; ++e) {
    const float f = src[e];
    const unsigned hb = __float_as_uint(f) & 0xffff0000u;
    const float f1 = f - __uint_as_float(hb);
    const unsigned mb = __float_as_uint(f1) & 0xffff0000u;
    const float f2 = f1 - __uint_as_float(mb);
    ph[e] = (u16)(hb >> 16);
    pm[e] = (u16)(mb >> 16);
    pl[e] = (u16)(__float_as_uint(f2) >> 16);
  }
}

// ============ decoder kernel: fp32, bit-exact, 8 rows/wave (R0 math) ======
__launch_bounds__(256, 2)
__global__ void dec_kernel(const float* __restrict__ x,
                           const float* __restrict__ unoise,
                           const float* __restrict__ dbhh,
                           const float* __restrict__ dbe2d,
                           const float* __restrict__ ws,
                           u8* __restrict__ tokhist,
                           float* __restrict__ out) {
  const float* WdhhT  = ws + kOffWdhhT;
  const float* We2dT  = ws + kOffWe2dT;
  const float* DecTab = ws + kOffDecTab;

  __shared__ __align__(16) float hd_s[4][kE][8];  // 32KB: wave-private state

  const int tid  = (int)threadIdx.x;
  const int w    = tid >> 6;
  const int jx   = tid & 63;
  const int row0 = (int)blockIdx.x * 32 + w * 8;  // 8 rows per wave
  const int e0   = jx * 4;

  float (*hd)[8] = hd_s[w];

  // init: hdec = x (coalesced)
  for (int i = jx; i < kE * 8; i += 64) {
    const int r = i >> 8, k = i & (kE - 1);
    hd[k][r] = x[(size_t)(row0 + r) * kE + k];
  }

  int tok[8], Nn[8];
  bool alive[8];
#pragma unroll
  for (int r = 0; r < 8; ++r) { tok[r] = kV; Nn[r] = kT; alive[r] = true; }

  const float4 dbr = *(const float4*)(dbhh + e0);
  const float4 dbz = *(const float4*)(dbhh + 256 + e0);
  const float4 dbn = *(const float4*)(dbhh + 512 + e0);
  const float2 be2 = *(const float2*)(dbe2d + 2 * jx);

  const size_t uttN = (size_t)kB * kT * kV;
  float acc[8][3][4];

  for (int t = 0; t < kT; ++t) {
    __syncthreads();  // keep block waves in phase: L1 reuse of WdhhT stream

    // ---- GRU gh = h @ Whh^T (FMA order identical to proven kernel) ----
#pragma unroll
    for (int r = 0; r < 8; ++r)
#pragma unroll
      for (int g = 0; g < 3; ++g)
#pragma unroll
        for (int c = 0; c < 4; ++c) acc[r][g][c] = 0.0f;
#pragma unroll 2
    for (int k = 0; k < kE; ++k) {
      const float4 hA = *(const float4*)(&hd[k][0]);
      const float4 hB = *(const float4*)(&hd[k][4]);
      const float* wp = WdhhT + k * kG3 + e0;
      const float4 w0 = *(const float4*)(wp);
      const float4 w1 = *(const float4*)(wp + 256);
      const float4 w2 = *(const float4*)(wp + 512);
      const float hv[8] = {hA.x, hA.y, hA.z, hA.w, hB.x, hB.y, hB.z, hB.w};
      const float wv[3][4] = {{w0.x, w0.y, w0.z, w0.w},
                              {w1.x, w1.y, w1.z, w1.w},
                              {w2.x, w2.y, w2.z, w2.w}};
#pragma unroll
      for (int r = 0; r < 8; ++r)
#pragma unroll
        for (int g = 0; g < 3; ++g)
#pragma unroll
          for (int c = 0; c < 4; ++c)
            acc[r][g][c] = fmaf(hv[r], wv[g][c], acc[r][g][c]);
    }

    // ---- pointwise gates + state update ----
    {
      const float br[4] = {dbr.x, dbr.y, dbr.z, dbr.w};
      const float bz[4] = {dbz.x, dbz.y, dbz.z, dbz.w};
      const float bn[4] = {dbn.x, dbn.y, dbn.z, dbn.w};
#pragma unroll
      for (int r = 0; r < 8; ++r) {
        const float* gp = DecTab + tok[r] * kG3 + e0;
        const float4 g0 = *(const float4*)(gp);
        const float4 g1 = *(const float4*)(gp + 256);
        const float4 g2 = *(const float4*)(gp + 512);
        const float gi[3][4] = {{g0.x, g0.y, g0.z, g0.w},
                                {g1.x, g1.y, g1.z, g1.w},
                                {g2.x, g2.y, g2.z, g2.w}};
#pragma unroll
        for (int c = 0; c < 4; ++c) {
          const float rg = sigmf(gi[0][c] + acc[r][0][c] + br[c]);
          const float zg = sigmf(gi[1][c] + acc[r][1][c] + bz[c]);
          const float ng = tanhf(gi[2][c] + rg * (acc[r][2][c] + bn[c]));
          acc[r][0][c] = ng;
          acc[r][1][c] = zg;
        }
      }
#pragma unroll
      for (int c = 0; c < 4; ++c) {
        const int e = e0 + c;
        const float4 hA = *(const float4*)(&hd[e][0]);
        const float4 hB = *(const float4*)(&hd[e][4]);
        const float ho[8] = {hA.x, hA.y, hA.z, hA.w, hB.x, hB.y, hB.z, hB.w};
        float hn[8];
#pragma unroll
        for (int r = 0; r < 8; ++r)
          hn[r] = (1.0f - acc[r][1][c]) * acc[r][0][c] + acc[r][1][c] * ho[r];
        *(float4*)(&hd[e][0]) = make_float4(hn[0], hn[1], hn[2], hn[3]);
        *(float4*)(&hd[e][4]) = make_float4(hn[4], hn[5], hn[6], hn[7]);
      }
    }

    // ---- logits + gumbel + argmax; lane covers cols 2jx, 2jx+1 ----
    float l0[8], l1[8];
#pragma unroll
    for (int r = 0; r < 8; ++r) { l0[r] = 0.0f; l1[r] = 0.0f; }
#pragma unroll 8
    for (int k = 0; k < kE; ++k) {
      const float4 hA = *(const float4*)(&hd[k][0]);
      const float4 hB = *(const float4*)(&hd[k][4]);
      const float2 wv = *(const float2*)(We2dT + k * kV + 2 * jx);
      const float hv[8] = {hA.x, hA.y, hA.z, hA.w, hB.x, hB.y, hB.z, hB.w};
#pragma unroll
      for (int r = 0; r < 8; ++r) {
        l0[r] = fmaf(hv[r], wv.x, l0[r]);
        l1[r] = fmaf(hv[r], wv.y, l1[r]);
      }
    }
    const float* up = unoise + ((size_t)t * kB + row0) * kV + 2 * jx;
#pragma unroll
    for (int r = 0; r < 8; ++r) {
      const float2 u = *(const float2*)(up + (size_t)r * kV);
      const float a0 = l0[r] + be2.x + gumbelf(u.x);
      const float a1 = l1[r] + be2.y + gumbelf(u.y);
      float mv; int mi;
      if (a1 > a0) { mv = a1; mi = 2 * jx + 1; } else { mv = a0; mi = 2 * jx; }
#pragma unroll
      for (int off = 32; off >= 1; off >>= 1) {
        const float ov = __shfl_xor(mv, off, 64);
        const int   oi = __shfl_xor(mi, off, 64);
        if (ov > mv || (ov == mv && oi < mi)) { mv = ov; mi = oi; }
      }
      const bool ended = (mi == 0);
      if (ended) Nn[r] = (Nn[r] < t) ? Nn[r] : t;
      const bool anew = alive[r] && !ended;
      alive[r] = anew;
      tok[r] = __builtin_amdgcn_readfirstlane(anew ? mi : kV);  // wave-uniform
      if (jx == r) tokhist[(size_t)t * kB + row0 + r] = (u8)tok[r];
      float2 pr;
      pr.x = (anew && mi == 2 * jx) ? 1.0f : 0.0f;
      pr.y = (anew && mi == 2 * jx + 1) ? 1.0f : 0.0f;
      *reinterpret_cast<float2*>(
          out + ((size_t)(row0 + r) * kT + t) * kV + 2 * jx) = pr;
    }
  }

  // ---- N output ----
#pragma unroll
  for (int r = 0; r < 8; ++r)
    if (jx == r) out[uttN + row0 + r] = (float)Nn[r];
}

// ==== encoder kernel: MFMA, 16 rows/block, DIRECT B loads (no prefetch) ===
__launch_bounds__(256, 2)
__global__ void enc_kernel(const float* __restrict__ ebhh,
                           const float* __restrict__ ws,
                           const u8* __restrict__ tokhist,
                           float* __restrict__ out) {
  const float* EncTab = ws + kOffEncTab;
  const u16* Bh_t = (const u16*)(ws + kOffBTab);
  const u16* Bm_t = Bh_t + kBCount;
  const u16* Bl_t = Bh_t + 2 * kBCount;

  __shared__ __align__(16) float henc[16 * kE];  // 16KB block-shared, swizzled

  const int tid  = (int)threadIdx.x;
  const int w    = tid >> 6;
  const int jx   = tid & 63;
  const int brow0 = (int)blockIdx.x * 16;

  for (int i = tid; i < 16 * kE; i += 256) henc[i] = 0.0f;
  __syncthreads();

  // per-lane constants (MFMA D layout: col=lane&15, row=(lane>>4)*4+reg)
  const int l15  = jx & 15;
  const int ksub = jx >> 4;
  const int abase = l15 * kE;   // A-row = l15 (single 16-row M-tile)
  const int am7 = l15 & 7;
  float ebr[4], ebz[4], ebn[4];
#pragma unroll
  for (int nn = 0; nn < 4; ++nn) {
    const int ec = (w << 6) + (nn << 4) + l15;
    ebr[nn] = ebhh[ec];
    ebz[nn] = ebhh[kE + ec];
    ebn[nn] = ebhh[2 * kE + ec];
  }

  const size_t uttN = (size_t)kB * kT * kV;
  const f32x4 zero4 = {0.0f, 0.0f, 0.0f, 0.0f};

  for (int t = 0; t < kT; ++t) {
    // ---- gh = henc @ eWhh^T via MFMA; 3 live B-frags only (no spill) ----
    f32x4 eacc[12];
#pragma unroll
    for (int nt = 0; nt < 12; ++nt) eacc[nt] = zero4;

#pragma unroll
    for (int kt = 0; kt < 8; ++kt) {
      const int c0 = ((kt << 2) + ksub) ^ am7;
      const float4 f00 = *(const float4*)&henc[abase + (c0 << 3)];
      const float4 f01 = *(const float4*)&henc[abase + (c0 << 3) + 4];
      const Bf3 A = split3(f00, f01);
      const int recb = (((kt << 2) + ksub) * kG3 + (w << 6) + l15) * 8;
#pragma unroll
      for (int nt = 0; nt < 12; ++nt) {
        const int off = recb + ((nt >> 2) * 256 + (nt & 3) * 16) * 8;
        const bf16x8 Bh = *reinterpret_cast<const bf16x8*>(Bh_t + off);
        const bf16x8 Bm = *reinterpret_cast<const bf16x8*>(Bm_t + off);
        const bf16x8 Bl = *reinterpret_cast<const bf16x8*>(Bl_t + off);
        // per-accumulator product order identical to R2/R6
        eacc[nt] = mfma16(A.h, Bh, eacc[nt]);
        eacc[nt] = mfma16(A.h, Bm, eacc[nt]);
        eacc[nt] = mfma16(A.m, Bh, eacc[nt]);
        eacc[nt] = mfma16(A.h, Bl, eacc[nt]);
        eacc[nt] = mfma16(A.l, Bh, eacc[nt]);
        eacc[nt] = mfma16(A.m, Bm, eacc[nt]);
      }
    }
    __syncthreads();  // all waves done READING henc

    // ---- pointwise: gates + state update (writes henc) ----
#pragma unroll
    for (int j2 = 0; j2 < 4; ++j2) {
      const int row = (ksub << 2) + j2;
      const int tk = (int)tokhist[(size_t)t * kB + brow0 + row];
      const float* gp = EncTab + tk * kG3;
#pragma unroll
      for (int nn = 0; nn < 4; ++nn) {
        const int ec = (w << 6) + (nn << 4) + l15;
        const float rg = sigmf(gp[ec] + eacc[nn][j2] + ebr[nn]);
        const float zg = sigmf(gp[kE + ec] + eacc[4 + nn][j2] + ebz[nn]);
        const float ng = tanhf(gp[2 * kE + ec] + rg * (eacc[8 + nn][j2] + ebn[nn]));
        const int hx = hidx(row, ec);
        const float ho = henc[hx];
        henc[hx] = (1.0f - zg) * ng + zg * ho;
      }
    }
    __syncthreads();  // henc writes done before next step's MFMA reads
  }

  // ---- reconst = final henc ----
  for (int i = tid; i < 16 * kE; i += 256) {
    const int row = i >> 8, col = i & (kE - 1);
    out[uttN + kB + (size_t)(brow0 + row) * kE + col] = henc[hidx(row, col)];
  }
}

extern "C" void kernel_launch(void* const* d_in, const int* in_sizes, int n_in,
                              void* d_out, int out_size, void* d_ws, size_t ws_size,
                              hipStream_t stream) {
  (void)in_sizes; (void)n_in; (void)out_size; (void)ws_size;
  const float* x      = (const float*)d_in[0];
  // d_in[1] = global_idxes (unused by reference)
  const float* unoise = (const float*)d_in[2];
  const float* dWd2e  = (const float*)d_in[3];
  const float* dbd2e  = (const float*)d_in[4];
  const float* dWih   = (const float*)d_in[5];
  const float* dWhh   = (const float*)d_in[6];
  const float* dbih   = (const float*)d_in[7];
  const float* dbhh   = (const float*)d_in[8];
  const float* dWe2d  = (const float*)d_in[9];
  const float* dbe2d  = (const float*)d_in[10];
  const float* eWd2e  = (const float*)d_in[11];
  const float* ebd2e  = (const float*)d_in[12];
  const float* eWih   = (const float*)d_in[13];
  const float* eWhh   = (const float*)d_in[14];
  const float* ebih   = (const float*)d_in[15];
  const float* ebhh   = (const float*)d_in[16];
  float* ws = (float*)d_ws;  // needs 3,151,872 bytes (~3.0 MB)
  u8* tokhist = (u8*)(ws + kOffTok);

  prep_transpose<<<896, 256, 0, stream>>>(dWhh, dWe2d, ws);
  prep_tables<<<(129 * kG3 + 255) / 256, 256, 0, stream>>>(
      dWih, dWd2e, dbd2e, dbih, ws + kOffDecTab);
  prep_tables<<<(129 * kG3 + 255) / 256, 256, 0, stream>>>(
      eWih, eWd2e, ebd2e, ebih, ws + kOffEncTab);
  prep_bsplit<<<(32 * kG3 + 255) / 256, 256, 0, stream>>>(
      eWhh, (u16*)(ws + kOffBTab));
  dec_kernel<<<kB / 32, 256, 0, stream>>>(
      x, unoise, dbhh, dbe2d, ws, tokhist, (float*)d_out);
  enc_kernel<<<kB / 16, 256, 0, stream>>>(
      ebhh, ws, tokhist, (float*)d_out);
}

// Round 8
// 3541.641 us; speedup vs baseline: 1.9285x; 1.9285x over previous
//
#include <hip/hip_runtime.h>

// GumbelDecoderEncoder: B=16384, E=256, V=128, T=16, TAU=1.
// Key facts exploited:
//  * y is numerically EXACTLY one-hot or zero, so input-side matmuls are
//    table lookups (DecTab/EncTab row 128 = zero-token case).
//  * argmax(softmax((l+g)/tau)) == argmax(l+g).
//  * Encoder sieve can never fire: reconst = final encoder state.
//  * Row-independent; decoder hidden state is wave-private LDS.
// History: enc HBM fetch scales with table demand (= blocks*16*1.15MB):
// R6 512blk->5.6GB, R7 1024blk->9.3GB fetch, ~50% miss; WRITE ~1.1-1.8GB =
// accumulator scratch round-trips at the 128-arch-VGPR cap. Both pipes <8%.
// R8 (this round): enc restructured to amortize the table 4x and fit regs:
//  * 64 rows/block (256 blocks, 1/CU): table demand 18.9 -> 4.7 GB.
//  * 8 waves x 512 thr; wave owns 32 cols/gate (6 N-tiles) x 4 M-tiles:
//    eacc[4][6] = 96 regs -> AGPRs; arch ~120 (A 48 + B-rotation 36 + misc).
//  * 3-buffer rotating B prefetch, depth 2 (~240cy >= L2 latency); each
//    B-triple feeds 24 MFMAs.
//  * Per-accumulator product order unchanged (hh,hm,mh,hl,lh,mm; kt 0..7)
//    -> encoder numerics identical to R2..R7 (absmax pinned).
//  * dec_kernel frozen (R7-proven, ~1.9ms, bit-exact).
// ws: 722432 floats + 256KB tok = 3,151,872 bytes.

namespace {
constexpr int kB  = 16384;
constexpr int kE  = 256;
constexpr int kV  = 128;
constexpr int kT  = 16;
constexpr int kG3 = 768;

constexpr int kOffWdhhT  = 0;                       // [256][768] f32 dec Whh^T (k-major)
constexpr int kOffWe2dT  = kG3 * kE;                // [256][128] f32
constexpr int kOffDecTab = kOffWe2dT + kV * kE;     // [129][768] f32
constexpr int kOffEncTab = kOffDecTab + 129 * kG3;  // [129][768] f32
constexpr int kOffBTab   = kOffEncTab + 129 * kG3;  // enc Whh bf16 3-split (u16)
constexpr int kBCount    = 32 * kG3 * 8;            // 196608 u16 per split level
constexpr int kOffTok    = kOffBTab + (3 * kBCount) / 2;  // [16][16384] u8
// ws bytes: 722432*4 + 262144 = 3,151,872
}

typedef short bf16x8 __attribute__((ext_vector_type(8)));  // 8 bf16 as i16 (4 VGPRs)
typedef float f32x4  __attribute__((ext_vector_type(4)));
typedef unsigned short u16;
typedef unsigned char u8;

__device__ __forceinline__ float sigmf(float v) { return 1.0f / (1.0f + expf(-v)); }
__device__ __forceinline__ float gumbelf(float u) {
  return -logf(-logf(u + 1e-10f) + 1e-10f);
}

__device__ __forceinline__ f32x4 mfma16(bf16x8 a, bf16x8 b, f32x4 c) {
  return __builtin_amdgcn_mfma_f32_16x16x32_bf16(a, b, c, 0, 0, 0);
}

struct Bf3 { bf16x8 h, m, l; };

// exact 3-way bf16 split: f = hi + mid + f2 exactly (truncating Dekker split),
// lo = trunc-to-bf16(f2); dropped bits are < 2^-24 relative.
__device__ __forceinline__ Bf3 split3(float4 a, float4 b) {
  const float v[8] = {a.x, a.y, a.z, a.w, b.x, b.y, b.z, b.w};
  union { bf16x8 b8; u16 u[8]; } H, M, L;
#pragma unroll
  for (int e = 0; e < 8; ++e) {
    const float f = v[e];
    const unsigned hb = __float_as_uint(f) & 0xffff0000u;
    const float f1 = f - __uint_as_float(hb);
    const unsigned mb = __float_as_uint(f1) & 0xffff0000u;
    const float f2 = f1 - __uint_as_float(mb);
    H.u[e] = (u16)(hb >> 16);
    M.u[e] = (u16)(mb >> 16);
    L.u[e] = (u16)(__float_as_uint(f2) >> 16);
  }
  Bf3 r; r.h = H.b8; r.m = M.b8; r.l = L.b8;
  return r;
}

// swizzled henc index: 8-float chunks XORed by row&7 -> spread A-read banks
__device__ __forceinline__ int hidx(int row, int col) {
  return row * kE + ((((col >> 3) ^ (row & 7)) << 3) | (col & 7));
}

// ---- prepass 1: k-major transposes of dec Whh and We2d ----
__global__ void prep_transpose(const float* __restrict__ dWhh,
                               const float* __restrict__ We2d,
                               float* __restrict__ ws) {
  const int n1 = kG3 * kE;
  const int n2 = n1 + kV * kE;
  for (int i = blockIdx.x * blockDim.x + threadIdx.x; i < n2;
       i += gridDim.x * blockDim.x) {
    if (i < n1) {
      const int k = i / kG3, j = i - k * kG3;
      ws[i] = dWhh[j * kE + k];
    } else {
      const int t = i - n1;
      const int k = t / kV, v = t - k * kV;
      ws[i] = We2d[v * kE + k];
    }
  }
}

// ---- prepass 2: token->gi tables (v==128 is the zero-token row) ----
__global__ void prep_tables(const float* __restrict__ Wih,
                            const float* __restrict__ Wd2e,
                            const float* __restrict__ bd2e,
                            const float* __restrict__ bih,
                            float* __restrict__ tab) {
  const int i = blockIdx.x * blockDim.x + threadIdx.x;
  if (i >= 129 * kG3) return;
  const int v = i / kG3, j = i - v * kG3;
  const float* wr = Wih + j * kE;
  float acc = 0.0f;
  if (v < kV) {
    for (int k = 0; k < kE; ++k) acc = fmaf(wr[k], Wd2e[k * kV + v] + bd2e[k], acc);
  } else {
    for (int k = 0; k < kE; ++k) acc = fmaf(wr[k], bd2e[k], acc);
  }
  tab[i] = acc + bih[j];
}

// ---- prepass 3: enc Whh^T -> bf16 3-way split MFMA B-fragment table ----
// record idx = kg*768 + j (kg = k/8), holds e=0..7 with k = kg*8+e.
__global__ void prep_bsplit(const float* __restrict__ eWhh,
                            u16* __restrict__ bt) {
  const int idx = blockIdx.x * blockDim.x + threadIdx.x;
  if (idx >= 32 * kG3) return;
  const int j = idx % kG3;
  const int kg = idx / kG3;
  u16* ph = bt + (size_t)idx * 8;
  u16* pm = ph + kBCount;
  u16* pl = pm + kBCount;
  const float* src = eWhh + j * kE + kg * 8;
#pragma unroll
  for (int e = 0; e < 8; ++e) {
    const float f = src[e];
    const unsigned hb = __float_as_uint(f) & 0xffff0000u;
    const float f1 = f - __uint_as_float(hb);
    const unsigned mb = __float_as_uint(f1) & 0xffff0000u;
    const float f2 = f1 - __uint_as_float(mb);
    ph[e] = (u16)(hb >> 16);
    pm[e] = (u16)(mb >> 16);
    pl[e] = (u16)(__float_as_uint(f2) >> 16);
  }
}

// ============ decoder kernel: fp32, bit-exact, 8 rows/wave (R0 math) ======
__launch_bounds__(256, 2)
__global__ void dec_kernel(const float* __restrict__ x,
                           const float* __restrict__ unoise,
                           const float* __restrict__ dbhh,
                           const float* __restrict__ dbe2d,
                           const float* __restrict__ ws,
                           u8* __restrict__ tokhist,
                           float* __restrict__ out) {
  const float* WdhhT  = ws + kOffWdhhT;
  const float* We2dT  = ws + kOffWe2dT;
  const float* DecTab = ws + kOffDecTab;

  __shared__ __align__(16) float hd_s[4][kE][8];  // 32KB: wave-private state

  const int tid  = (int)threadIdx.x;
  const int w    = tid >> 6;
  const int jx   = tid & 63;
  const int row0 = (int)blockIdx.x * 32 + w * 8;  // 8 rows per wave
  const int e0   = jx * 4;

  float (*hd)[8] = hd_s[w];

  // init: hdec = x (coalesced)
  for (int i = jx; i < kE * 8; i += 64) {
    const int r = i >> 8, k = i & (kE - 1);
    hd[k][r] = x[(size_t)(row0 + r) * kE + k];
  }

  int tok[8], Nn[8];
  bool alive[8];
#pragma unroll
  for (int r = 0; r < 8; ++r) { tok[r] = kV; Nn[r] = kT; alive[r] = true; }

  const float4 dbr = *(const float4*)(dbhh + e0);
  const float4 dbz = *(const float4*)(dbhh + 256 + e0);
  const float4 dbn = *(const float4*)(dbhh + 512 + e0);
  const float2 be2 = *(const float2*)(dbe2d + 2 * jx);

  const size_t uttN = (size_t)kB * kT * kV;
  float acc[8][3][4];

  for (int t = 0; t < kT; ++t) {
    __syncthreads();  // keep block waves in phase: L1 reuse of WdhhT stream

    // ---- GRU gh = h @ Whh^T (FMA order identical to proven kernel) ----
#pragma unroll
    for (int r = 0; r < 8; ++r)
#pragma unroll
      for (int g = 0; g < 3; ++g)
#pragma unroll
        for (int c = 0; c < 4; ++c) acc[r][g][c] = 0.0f;
#pragma unroll 2
    for (int k = 0; k < kE; ++k) {
      const float4 hA = *(const float4*)(&hd[k][0]);
      const float4 hB = *(const float4*)(&hd[k][4]);
      const float* wp = WdhhT + k * kG3 + e0;
      const float4 w0 = *(const float4*)(wp);
      const float4 w1 = *(const float4*)(wp + 256);
      const float4 w2 = *(const float4*)(wp + 512);
      const float hv[8] = {hA.x, hA.y, hA.z, hA.w, hB.x, hB.y, hB.z, hB.w};
      const float wv[3][4] = {{w0.x, w0.y, w0.z, w0.w},
                              {w1.x, w1.y, w1.z, w1.w},
                              {w2.x, w2.y, w2.z, w2.w}};
#pragma unroll
      for (int r = 0; r < 8; ++r)
#pragma unroll
        for (int g = 0; g < 3; ++g)
#pragma unroll
          for (int c = 0; c < 4; ++c)
            acc[r][g][c] = fmaf(hv[r], wv[g][c], acc[r][g][c]);
    }

    // ---- pointwise gates + state update ----
    {
      const float br[4] = {dbr.x, dbr.y, dbr.z, dbr.w};
      const float bz[4] = {dbz.x, dbz.y, dbz.z, dbz.w};
      const float bn[4] = {dbn.x, dbn.y, dbn.z, dbn.w};
#pragma unroll
      for (int r = 0; r < 8; ++r) {
        const float* gp = DecTab + tok[r] * kG3 + e0;
        const float4 g0 = *(const float4*)(gp);
        const float4 g1 = *(const float4*)(gp + 256);
        const float4 g2 = *(const float4*)(gp + 512);
        const float gi[3][4] = {{g0.x, g0.y, g0.z, g0.w},
                                {g1.x, g1.y, g1.z, g1.w},
                                {g2.x, g2.y, g2.z, g2.w}};
#pragma unroll
        for (int c = 0; c < 4; ++c) {
          const float rg = sigmf(gi[0][c] + acc[r][0][c] + br[c]);
          const float zg = sigmf(gi[1][c] + acc[r][1][c] + bz[c]);
          const float ng = tanhf(gi[2][c] + rg * (acc[r][2][c] + bn[c]));
          acc[r][0][c] = ng;
          acc[r][1][c] = zg;
        }
      }
#pragma unroll
      for (int c = 0; c < 4; ++c) {
        const int e = e0 + c;
        const float4 hA = *(const float4*)(&hd[e][0]);
        const float4 hB = *(const float4*)(&hd[e][4]);
        const float ho[8] = {hA.x, hA.y, hA.z, hA.w, hB.x, hB.y, hB.z, hB.w};
        float hn[8];
#pragma unroll
        for (int r = 0; r < 8; ++r)
          hn[r] = (1.0f - acc[r][1][c]) * acc[r][0][c] + acc[r][1][c] * ho[r];
        *(float4*)(&hd[e][0]) = make_float4(hn[0], hn[1], hn[2], hn[3]);
        *(float4*)(&hd[e][4]) = make_float4(hn[4], hn[5], hn[6], hn[7]);
      }
    }

    // ---- logits + gumbel + argmax; lane covers cols 2jx, 2jx+1 ----
    float l0[8], l1[8];
#pragma unroll
    for (int r = 0; r < 8; ++r) { l0[r] = 0.0f; l1[r] = 0.0f; }
#pragma unroll 8
    for (int k = 0; k < kE; ++k) {
      const float4 hA = *(const float4*)(&hd[k][0]);
      const float4 hB = *(const float4*)(&hd[k][4]);
      const float2 wv = *(const float2*)(We2dT + k * kV + 2 * jx);
      const float hv[8] = {hA.x, hA.y, hA.z, hA.w, hB.x, hB.y, hB.z, hB.w};
#pragma unroll
      for (int r = 0; r < 8; ++r) {
        l0[r] = fmaf(hv[r], wv.x, l0[r]);
        l1[r] = fmaf(hv[r], wv.y, l1[r]);
      }
    }
    const float* up = unoise + ((size_t)t * kB + row0) * kV + 2 * jx;
#pragma unroll
    for (int r = 0; r < 8; ++r) {
      const float2 u = *(const float2*)(up + (size_t)r * kV);
      const float a0 = l0[r] + be2.x + gumbelf(u.x);
      const float a1 = l1[r] + be2.y + gumbelf(u.y);
      float mv; int mi;
      if (a1 > a0) { mv = a1; mi = 2 * jx + 1; } else { mv = a0; mi = 2 * jx; }
#pragma unroll
      for (int off = 32; off >= 1; off >>= 1) {
        const float ov = __shfl_xor(mv, off, 64);
        const int   oi = __shfl_xor(mi, off, 64);
        if (ov > mv || (ov == mv && oi < mi)) { mv = ov; mi = oi; }
      }
      const bool ended = (mi == 0);
      if (ended) Nn[r] = (Nn[r] < t) ? Nn[r] : t;
      const bool anew = alive[r] && !ended;
      alive[r] = anew;
      tok[r] = __builtin_amdgcn_readfirstlane(anew ? mi : kV);  // wave-uniform
      if (jx == r) tokhist[(size_t)t * kB + row0 + r] = (u8)tok[r];
      float2 pr;
      pr.x = (anew && mi == 2 * jx) ? 1.0f : 0.0f;
      pr.y = (anew && mi == 2 * jx + 1) ? 1.0f : 0.0f;
      *reinterpret_cast<float2*>(
          out + ((size_t)(row0 + r) * kT + t) * kV + 2 * jx) = pr;
    }
  }

  // ---- N output ----
#pragma unroll
  for (int r = 0; r < 8; ++r)
    if (jx == r) out[uttN + row0 + r] = (float)Nn[r];
}

// === encoder kernel: MFMA, 64 rows/block, 8 waves, AGPR acc, rot-prefetch ==
__launch_bounds__(512, 2)
__global__ void enc_kernel(const float* __restrict__ ebhh,
                           const float* __restrict__ ws,
                           const u8* __restrict__ tokhist,
                           float* __restrict__ out) {
  const float* EncTab = ws + kOffEncTab;
  const u16* Bh_t = (const u16*)(ws + kOffBTab);
  const u16* Bm_t = Bh_t + kBCount;
  const u16* Bl_t = Bh_t + 2 * kBCount;

  __shared__ __align__(16) float henc[64 * kE];  // 64KB block-shared, swizzled

  const int tid  = (int)threadIdx.x;
  const int w    = tid >> 6;          // 8 waves; wave owns cols [32w,32w+32) per gate
  const int jx   = tid & 63;
  const int brow0 = (int)blockIdx.x * 64;

  for (int i = tid; i < 64 * kE; i += 512) henc[i] = 0.0f;
  __syncthreads();

  // per-lane constants (MFMA D layout: col=lane&15, row=(lane>>4)*4+reg)
  const int l15  = jx & 15;
  const int ksub = jx >> 4;
  const int am7  = l15 & 7;
  float ebr[2], ebz[2], ebn[2];
#pragma unroll
  for (int nn = 0; nn < 2; ++nn) {
    const int ec = (w << 5) + (nn << 4) + l15;
    ebr[nn] = ebhh[ec];
    ebz[nn] = ebhh[kE + ec];
    ebn[nn] = ebhh[2 * kE + ec];
  }

  const size_t uttN = (size_t)kB * kT * kV;
  const f32x4 zero4 = {0.0f, 0.0f, 0.0f, 0.0f};

  // N-tile nt in [0,6): gate = nt>>1, subcol = (nt&1)*16; col = gate*256 +
  // (w<<5) + subcol + l15.  B record idx = ((kt*4+ksub)*768 + col) * 8.
#define LDB(B_, kt_, nt_)                                                     \
  {                                                                           \
    const int off_ = ((((kt_) << 2) + ksub) * kG3 + ((nt_) >> 1) * 256 +      \
                      (w << 5) + (((nt_) & 1) << 4) + l15) * 8;               \
    B_[0] = *reinterpret_cast<const bf16x8*>(Bh_t + off_);                    \
    B_[1] = *reinterpret_cast<const bf16x8*>(Bm_t + off_);                    \
    B_[2] = *reinterpret_cast<const bf16x8*>(Bl_t + off_);                    \
  }
  // prefetch group (kt_, nt_) with nt_ possibly >= 6 (wraps to kt_+1)
#define PRE(B_, kt_, nt_)                                                     \
  {                                                                           \
    if ((nt_) < 6) {                                                          \
      LDB(B_, kt_, nt_)                                                       \
    } else if ((kt_) + 1 < 8) {                                               \
      LDB(B_, (kt_) + 1, (nt_) - 6)                                           \
    }                                                                         \
  }
  // A fragments for all 4 M-tiles at this kt (rows mt*16 + l15)
#define AFRAG4(kt_)                                                           \
  {                                                                           \
    const int c_ = (((kt_) << 2) + ksub) ^ am7;                               \
    _Pragma("unroll")                                                         \
    for (int mt = 0; mt < 4; ++mt) {                                          \
      const int base_ = ((mt << 4) + l15) * kE;                               \
      const float4 f0 = *(const float4*)&henc[base_ + (c_ << 3)];             \
      const float4 f1 = *(const float4*)&henc[base_ + (c_ << 3) + 4];         \
      A[mt] = split3(f0, f1);                                                 \
    }                                                                         \
  }
  // 24 MFMAs: per-accumulator product order hh,hm,mh,hl,lh,mm (as R2..R7);
  // mt-interleaved within each product for MFMA-pipe independence.
#define MF(B_, nt_)                                                           \
  {                                                                           \
    const bf16x8 Bh = B_[0], Bm = B_[1], Bl = B_[2];                          \
    _Pragma("unroll") for (int mt = 0; mt < 4; ++mt)                          \
      eacc[mt][nt_] = mfma16(A[mt].h, Bh, eacc[mt][nt_]);                     \
    _Pragma("unroll") for (int mt = 0; mt < 4; ++mt)                          \
      eacc[mt][nt_] = mfma16(A[mt].h, Bm, eacc[mt][nt_]);                     \
    _Pragma("unroll") for (int mt = 0; mt < 4; ++mt)                          \
      eacc[mt][nt_] = mfma16(A[mt].m, Bh, eacc[mt][nt_]);                     \
    _Pragma("unroll") for (int mt = 0; mt < 4; ++mt)                          \
      eacc[mt][nt_] = mfma16(A[mt].h, Bl, eacc[mt][nt_]);                     \
    _Pragma("unroll") for (int mt = 0; mt < 4; ++mt)                          \
      eacc[mt][nt_] = mfma16(A[mt].l, Bh, eacc[mt][nt_]);                     \
    _Pragma("unroll") for (int mt = 0; mt < 4; ++mt)                          \
      eacc[mt][nt_] = mfma16(A[mt].m, Bm, eacc[mt][nt_]);                     \
  }

  for (int t = 0; t < kT; ++t) {
    // ---- gh = henc @ eWhh^T via MFMA (4 M-tiles, 3-buffer rotation) ----
    f32x4 eacc[4][6];
#pragma unroll
    for (int mt = 0; mt < 4; ++mt)
#pragma unroll
      for (int nt = 0; nt < 6; ++nt) eacc[mt][nt] = zero4;

    bf16x8 b0[3], b1[3], b2[3];
    Bf3 A[4];
    LDB(b0, 0, 0) LDB(b1, 0, 1)
#pragma unroll
    for (int kt = 0; kt < 8; ++kt) {
      AFRAG4(kt)
      PRE(b2, kt, 2) MF(b0, 0)
      PRE(b0, kt, 3) MF(b1, 1)
      PRE(b1, kt, 4) MF(b2, 2)
      PRE(b2, kt, 5) MF(b0, 3)
      PRE(b0, kt, 6) MF(b1, 4)
      PRE(b1, kt, 7) MF(b2, 5)
    }
    __syncthreads();  // all waves done READING henc

    // ---- pointwise: gates + state update (writes henc) ----
#pragma unroll
    for (int mt = 0; mt < 4; ++mt) {
#pragma unroll
      for (int j2 = 0; j2 < 4; ++j2) {
        const int row = (mt << 4) + (ksub << 2) + j2;
        const int tk = (int)tokhist[(size_t)t * kB + brow0 + row];
        const float* gp = EncTab + tk * kG3;
#pragma unroll
        for (int nn = 0; nn < 2; ++nn) {
          const int ec = (w << 5) + (nn << 4) + l15;
          const float rg = sigmf(gp[ec] + eacc[mt][nn][j2] + ebr[nn]);
          const float zg = sigmf(gp[kE + ec] + eacc[mt][2 + nn][j2] + ebz[nn]);
          const float ng = tanhf(gp[2 * kE + ec] + rg * (eacc[mt][4 + nn][j2] + ebn[nn]));
          const int hx = hidx(row, ec);
          const float ho = henc[hx];
          henc[hx] = (1.0f - zg) * ng + zg * ho;
        }
      }
    }
    __syncthreads();  // henc writes done before next step's MFMA reads
  }

  // ---- reconst = final henc ----
  for (int i = tid; i < 64 * kE; i += 512) {
    const int row = i >> 8, col = i & (kE - 1);
    out[uttN + kB + (size_t)(brow0 + row) * kE + col] = henc[hidx(row, col)];
  }
#undef LDB
#undef PRE
#undef AFRAG4
#undef MF
}

extern "C" void kernel_launch(void* const* d_in, const int* in_sizes, int n_in,
                              void* d_out, int out_size, void* d_ws, size_t ws_size,
                              hipStream_t stream) {
  (void)in_sizes; (void)n_in; (void)out_size; (void)ws_size;
  const float* x      = (const float*)d_in[0];
  // d_in[1] = global_idxes (unused by reference)
  const float* unoise = (const float*)d_in[2];
  const float* dWd2e  = (const float*)d_in[3];
  const float* dbd2e  = (const float*)d_in[4];
  const float* dWih   = (const float*)d_in[5];
  const float* dWhh   = (const float*)d_in[6];
  const float* dbih   = (const float*)d_in[7];
  const float* dbhh   = (const float*)d_in[8];
  const float* dWe2d  = (const float*)d_in[9];
  const float* dbe2d  = (const float*)d_in[10];
  const float* eWd2e  = (const float*)d_in[11];
  const float* ebd2e  = (const float*)d_in[12];
  const float* eWih   = (const float*)d_in[13];
  const float* eWhh   = (const float*)d_in[14];
  const float* ebih   = (const float*)d_in[15];
  const float* ebhh   = (const float*)d_in[16];
  float* ws = (float*)d_ws;  // needs 3,151,872 bytes (~3.0 MB)
  u8* tokhist = (u8*)(ws + kOffTok);

  prep_transpose<<<896, 256, 0, stream>>>(dWhh, dWe2d, ws);
  prep_tables<<<(129 * kG3 + 255) / 256, 256, 0, stream>>>(
      dWih, dWd2e, dbd2e, dbih, ws + kOffDecTab);
  prep_tables<<<(129 * kG3 + 255) / 256, 256, 0, stream>>>(
      eWih, eWd2e, ebd2e, ebih, ws + kOffEncTab);
  prep_bsplit<<<(32 * kG3 + 255) / 256, 256, 0, stream>>>(
      eWhh, (u16*)(ws + kOffBTab));
  dec_kernel<<<kB / 32, 256, 0, stream>>>(
      x, unoise, dbhh, dbe2d, ws, tokhist, (float*)d_out);
  enc_kernel<<<kB / 64, 512, 0, stream>>>(
      ebhh, ws, tokhist, (float*)d_out);
}